// Round 2
// baseline (844.357 us; speedup 1.0000x reference)
//
#include <hip/hip_runtime.h>
#include <hip/hip_bf16.h>

#define N_NODES 50000
#define N_EDGES 1600000
#define IN_DIM  256
#define OUT_DIM 128
#define T_STEPS 8

typedef __attribute__((ext_vector_type(8))) short bf16x8;
typedef __attribute__((ext_vector_type(4))) float f32x4;

// ---- ws layout (bytes), fp32 pipeline ----
// h     : f32  [N*128]    @ 0           (25,600,000)
// Wt_hi : bf16 [128*256]  @ 25,600,000  (65,536)
// Wt_lo : bf16 [128*256]  @ 25,665,536  (65,536)
// cnt   : int  [N]        @ 25,731,072  (200,000)  } zeroed together
// fill  : int  [N]        @ 25,931,072  (200,000)  } (400,000 B memset)
// offs  : int  [N]        @ 26,131,072  (200,000)
// dinv  : f32  [N]        @ 26,331,072  (200,000)
// csr   : int  [E]        @ 26,531,072  (6,400,000)
// total ~33 MB

__device__ inline unsigned short bf_hi_trunc(float x) {
    return (unsigned short)(__float_as_uint(x) >> 16);
}
__device__ inline float bf_to_f(unsigned short u) {
    return __uint_as_float((unsigned)u << 16);
}
__device__ inline unsigned short f2bf_rne(float a) {
    __hip_bfloat16 t = __float2bfloat16(a);
    return *(unsigned short*)&t;
}

__global__ void k_prep_w(const float* __restrict__ W,
                         unsigned short* __restrict__ Wt_hi,
                         unsigned short* __restrict__ Wt_lo) {
    int idx = blockIdx.x * 256 + threadIdx.x;   // 32768 threads
    int n = idx >> 8;      // out dim
    int k = idx & 255;     // in dim
    float w = W[k * OUT_DIM + n];
    unsigned short hi = bf_hi_trunc(w);
    Wt_hi[idx] = hi;
    Wt_lo[idx] = f2bf_rne(w - bf_to_f(hi));
}

__global__ __launch_bounds__(256) void
k_gemm(const float* __restrict__ x,
       const unsigned short* __restrict__ Wt_hi,
       const unsigned short* __restrict__ Wt_lo,
       float* __restrict__ h) {
    int wave = blockIdx.x * 4 + (threadIdx.x >> 6);
    if (wave >= N_NODES / 16) return;           // 3125 M-tiles of 16 rows
    int lane = threadIdx.x & 63;
    int quad = lane >> 4;
    int r16  = lane & 15;
    int m0 = wave * 16;

    f32x4 acc[8];
#pragma unroll
    for (int nt = 0; nt < 8; ++nt) acc[nt] = (f32x4){0.f, 0.f, 0.f, 0.f};

#pragma unroll
    for (int kt = 0; kt < 8; ++kt) {
        int k0 = kt * 32 + quad * 8;
        // A frag: A[m=lane&15][k=quad*8+j] from fp32 x, split to bf16 hi/lo
        const float* xp = x + (size_t)(m0 + r16) * IN_DIM + k0;
        float4 v0 = *(const float4*)xp;
        float4 v1 = *(const float4*)(xp + 4);
        float vv[8] = {v0.x, v0.y, v0.z, v0.w, v1.x, v1.y, v1.z, v1.w};
        union { bf16x8 v; unsigned short u[8]; } ahi, alo;
#pragma unroll
        for (int j = 0; j < 8; ++j) {
            unsigned short hi = bf_hi_trunc(vv[j]);
            ahi.u[j] = hi;
            alo.u[j] = f2bf_rne(vv[j] - bf_to_f(hi));
        }
#pragma unroll
        for (int nt = 0; nt < 8; ++nt) {
            size_t woff = (size_t)(nt * 16 + r16) * IN_DIM + k0;
            bf16x8 bhi = *(const bf16x8*)(Wt_hi + woff);
            bf16x8 blo = *(const bf16x8*)(Wt_lo + woff);
            acc[nt] = __builtin_amdgcn_mfma_f32_16x16x32_bf16(ahi.v, bhi, acc[nt], 0, 0, 0);
            acc[nt] = __builtin_amdgcn_mfma_f32_16x16x32_bf16(alo.v, bhi, acc[nt], 0, 0, 0);
            acc[nt] = __builtin_amdgcn_mfma_f32_16x16x32_bf16(ahi.v, blo, acc[nt], 0, 0, 0);
        }
    }
    // C/D: col = lane&15, row = quad*4 + reg
#pragma unroll
    for (int nt = 0; nt < 8; ++nt) {
#pragma unroll
        for (int r = 0; r < 4; ++r) {
            int row = m0 + quad * 4 + r;
            int col = nt * 16 + r16;
            h[(size_t)row * OUT_DIM + col] = acc[nt][r];
        }
    }
}

__global__ void k_count(const int* __restrict__ edge, int* __restrict__ cnt) {
    int e = blockIdx.x * 256 + threadIdx.x;
    if (e < N_EDGES) atomicAdd(&cnt[edge[N_EDGES + e]], 1);
}

__global__ __launch_bounds__(1024) void
k_scan(const int* __restrict__ cnt, int* __restrict__ offs,
       float* __restrict__ dinv) {
    __shared__ int sdata[1024];
    int tid = threadIdx.x;
    int carry = 0;
    for (int base = 0; base < N_NODES; base += 1024) {
        int i = base + tid;
        int v = (i < N_NODES) ? cnt[i] : 0;
        if (i < N_NODES) dinv[i] = rsqrtf((float)(v + 1));  // deg = in-cnt + self loop
        sdata[tid] = v;
        __syncthreads();
        for (int off = 1; off < 1024; off <<= 1) {
            int t = (tid >= off) ? sdata[tid - off] : 0;
            __syncthreads();
            sdata[tid] += t;
            __syncthreads();
        }
        if (i < N_NODES) offs[i] = carry + sdata[tid] - v;  // exclusive
        carry += sdata[1023];
        __syncthreads();   // protect sdata[1023] before next-iter overwrite
    }
}

__global__ void k_fill(const int* __restrict__ edge, const int* __restrict__ offs,
                       int* __restrict__ fill, int* __restrict__ csr) {
    int e = blockIdx.x * 256 + threadIdx.x;
    if (e < N_EDGES) {
        int dst = edge[N_EDGES + e];
        int src = edge[e];
        int pos = offs[dst] + atomicAdd(&fill[dst], 1);
        csr[pos] = src;
    }
}

__global__ __launch_bounds__(256) void
k_agg_snn(const float* __restrict__ h,
          const int* __restrict__ offs, const int* __restrict__ cnt,
          const float* __restrict__ dinv, const int* __restrict__ csr,
          float* __restrict__ out) {
    int node = blockIdx.x * 4 + (threadIdx.x >> 6);   // one wave per node
    if (node >= N_NODES) return;
    int lane = threadIdx.x & 63;                      // lane handles dims 2l, 2l+1
    const float2* h2 = (const float2*)h;              // 64 float2 per row

    float di = dinv[node];
    // self-loop term: dinv[i] * h[i]
    float2 hv = h2[(size_t)node * 64 + lane];
    float a0 = di * hv.x;
    float a1 = di * hv.y;

    int beg = offs[node];
    int end = beg + cnt[node];
    for (int j = beg; j < end; ++j) {
        int s = csr[j];
        float w = dinv[s];
        float2 p = h2[(size_t)s * 64 + lane];
        a0 = fmaf(w, p.x, a0);
        a1 = fmaf(w, p.y, a1);
    }
    a0 *= di;
    a1 *= di;

    float u0 = a0 * 0.1f, u1 = a1 * 0.1f;   // STEP_SIZE
    float z0 = 0.f, z1 = 0.f;
    float2* out2 = (float2*)out;
    size_t baseo = (size_t)node * 64 + lane;
    const size_t plane = (size_t)N_NODES * 64;        // one t-plane in float2
#pragma unroll
    for (int t = 0; t < T_STEPS; ++t) {
        float H0 = z0 + (u0 - z0) * 0.5f;             // TAU = 2
        float H1 = z1 + (u1 - z1) * 0.5f;
        float o0 = (H0 >= 1.0f) ? 1.0f : 0.0f;        // V_THRESHOLD = 1
        float o1 = (H1 >= 1.0f) ? 1.0f : 0.0f;
        z0 = H0 - o0;
        z1 = H1 - o1;
        out2[(size_t)t * plane + baseo] = make_float2(o0, o1);             // o_seq
        out2[(size_t)(T_STEPS + t) * plane + baseo] = make_float2(z0, z1); // z_seq
    }
}

extern "C" void kernel_launch(void* const* d_in, const int* in_sizes, int n_in,
                              void* d_out, int out_size, void* d_ws, size_t ws_size,
                              hipStream_t stream) {
    const float* x  = (const float*)d_in[0];
    const float* W  = (const float*)d_in[1];
    const int*   ei = (const int*)d_in[2];
    float* out = (float*)d_out;

    char* ws = (char*)d_ws;
    float*          h     = (float*)(ws + 0);
    unsigned short* Wt_hi = (unsigned short*)(ws + 25600000);
    unsigned short* Wt_lo = (unsigned short*)(ws + 25665536);
    int*            cnt   = (int*)(ws + 25731072);
    int*            fill  = (int*)(ws + 25931072);
    int*            offs  = (int*)(ws + 26131072);
    float*          dinv  = (float*)(ws + 26331072);
    int*            csr   = (int*)(ws + 26531072);

    // zero cnt + fill (contiguous 400,000 B)
    hipMemsetAsync(ws + 25731072, 0, 400000, stream);

    k_prep_w<<<128, 256, 0, stream>>>(W, Wt_hi, Wt_lo);
    k_gemm<<<(3125 + 3) / 4, 256, 0, stream>>>(x, Wt_hi, Wt_lo, h);
    k_count<<<(N_EDGES + 255) / 256, 256, 0, stream>>>(ei, cnt);
    k_scan<<<1, 1024, 0, stream>>>(cnt, offs, dinv);
    k_fill<<<(N_EDGES + 255) / 256, 256, 0, stream>>>(ei, offs, fill, csr);
    k_agg_snn<<<N_NODES / 4, 256, 0, stream>>>(h, offs, cnt, dinv, csr, out);
}

// Round 3
// 789.381 us; speedup vs baseline: 1.0696x; 1.0696x over previous
//
#include <hip/hip_runtime.h>
#include <hip/hip_bf16.h>

#define N_NODES 50000
#define N_EDGES 1600000
#define IN_DIM  256
#define OUT_DIM 128
#define T_STEPS 8

typedef __attribute__((ext_vector_type(8))) short bf16x8;
typedef __attribute__((ext_vector_type(4))) float f32x4;

// ---- ws layout (bytes), fp32 pipeline ----
// h     : f32  [N*128]    @ 0            (25,600,000)
// hs    : bf16 [N*128]    @ 25,600,000   (12,800,000)  pre-scaled dinv[i]*h[i]
// Wt_hi : bf16 [128*256]  @ 38,400,000   (65,536)
// Wt_lo : bf16 [128*256]  @ 38,465,536   (65,536)
// cnt   : int  [N]        @ 38,531,072   (200,000)  } zeroed together
// fill  : int  [N]        @ 38,731,072   (200,000)  } (400,000 B memset)
// offs  : int  [N]        @ 38,931,072   (200,000)
// dinv  : f32  [N]        @ 39,131,072   (200,000)
// csr   : int  [E]        @ 39,331,072   (6,400,000)

__device__ inline unsigned short bf_hi_trunc(float x) {
    return (unsigned short)(__float_as_uint(x) >> 16);
}
__device__ inline float bf_to_f(unsigned short u) {
    return __uint_as_float((unsigned)u << 16);
}
__device__ inline unsigned short f2bf_rne(float a) {
    __hip_bfloat16 t = __float2bfloat16(a);
    return *(unsigned short*)&t;
}
__device__ inline float bf_lo(unsigned p) { return __uint_as_float(p << 16); }
__device__ inline float bf_hi(unsigned p) { return __uint_as_float(p & 0xffff0000u); }
__device__ inline unsigned pack2(float a, float b) {
    return (unsigned)f2bf_rne(a) | ((unsigned)f2bf_rne(b) << 16);
}

__global__ void k_prep_w(const float* __restrict__ W,
                         unsigned short* __restrict__ Wt_hi,
                         unsigned short* __restrict__ Wt_lo) {
    int idx = blockIdx.x * 256 + threadIdx.x;   // 32768 threads
    int n = idx >> 8;      // out dim
    int k = idx & 255;     // in dim
    float w = W[k * OUT_DIM + n];
    unsigned short hi = bf_hi_trunc(w);
    Wt_hi[idx] = hi;
    Wt_lo[idx] = f2bf_rne(w - bf_to_f(hi));
}

// GEMM (x @ W -> h, fp32 out) with the edge-dst histogram fused in:
// the non-returning atomics issue first and retire in the MFMA shadow.
__global__ __launch_bounds__(256) void
k_gemm_count(const float* __restrict__ x,
             const unsigned short* __restrict__ Wt_hi,
             const unsigned short* __restrict__ Wt_lo,
             float* __restrict__ h,
             const int* __restrict__ edge, int* __restrict__ cnt) {
    int tg = blockIdx.x * 256 + threadIdx.x;    // 200192 threads
    for (int e = tg; e < N_EDGES; e += 782 * 256)
        atomicAdd(&cnt[edge[N_EDGES + e]], 1);

    int wave = blockIdx.x * 4 + (threadIdx.x >> 6);
    if (wave >= N_NODES / 16) return;           // 3125 M-tiles of 16 rows
    int lane = threadIdx.x & 63;
    int quad = lane >> 4;
    int r16  = lane & 15;
    int m0 = wave * 16;

    f32x4 acc[8];
#pragma unroll
    for (int nt = 0; nt < 8; ++nt) acc[nt] = (f32x4){0.f, 0.f, 0.f, 0.f};

#pragma unroll
    for (int kt = 0; kt < 8; ++kt) {
        int k0 = kt * 32 + quad * 8;
        const float* xp = x + (size_t)(m0 + r16) * IN_DIM + k0;
        float4 v0 = *(const float4*)xp;
        float4 v1 = *(const float4*)(xp + 4);
        float vv[8] = {v0.x, v0.y, v0.z, v0.w, v1.x, v1.y, v1.z, v1.w};
        union { bf16x8 v; unsigned short u[8]; } ahi, alo;
#pragma unroll
        for (int j = 0; j < 8; ++j) {
            unsigned short hi = bf_hi_trunc(vv[j]);
            ahi.u[j] = hi;
            alo.u[j] = f2bf_rne(vv[j] - bf_to_f(hi));
        }
#pragma unroll
        for (int nt = 0; nt < 8; ++nt) {
            size_t woff = (size_t)(nt * 16 + r16) * IN_DIM + k0;
            bf16x8 bhi = *(const bf16x8*)(Wt_hi + woff);
            bf16x8 blo = *(const bf16x8*)(Wt_lo + woff);
            acc[nt] = __builtin_amdgcn_mfma_f32_16x16x32_bf16(ahi.v, bhi, acc[nt], 0, 0, 0);
            acc[nt] = __builtin_amdgcn_mfma_f32_16x16x32_bf16(alo.v, bhi, acc[nt], 0, 0, 0);
            acc[nt] = __builtin_amdgcn_mfma_f32_16x16x32_bf16(ahi.v, blo, acc[nt], 0, 0, 0);
        }
    }
#pragma unroll
    for (int nt = 0; nt < 8; ++nt) {
#pragma unroll
        for (int r = 0; r < 4; ++r) {
            int row = m0 + quad * 4 + r;
            int col = nt * 16 + r16;
            h[(size_t)row * OUT_DIM + col] = acc[nt][r];
        }
    }
}

// 50000-elem exclusive scan in one block: 49 serial items/thread + one
// 1024-wide LDS scan (replaces the 49x barrier-storm version).
__global__ __launch_bounds__(1024) void
k_scan(const int* __restrict__ cnt, int* __restrict__ offs,
       float* __restrict__ dinv) {
    __shared__ int sdata[1024];
    const int ITEMS = (N_NODES + 1023) / 1024;  // 49
    int tid = threadIdx.x;
    int start = tid * ITEMS;
    int end = min(start + ITEMS, N_NODES);
    int sum = 0;
    for (int i = start; i < end; ++i) sum += cnt[i];
    sdata[tid] = sum;
    __syncthreads();
    for (int off = 1; off < 1024; off <<= 1) {
        int t = (tid >= off) ? sdata[tid - off] : 0;
        __syncthreads();
        sdata[tid] += t;
        __syncthreads();
    }
    int run = sdata[tid] - sum;                 // exclusive base
    for (int i = start; i < end; ++i) {
        int v = cnt[i];
        offs[i] = run;
        dinv[i] = rsqrtf((float)(v + 1));       // deg = in-cnt + self loop
        run += v;
    }
}

// hs[i][d] = bf16(dinv[i] * h[i][d]) — removes the per-edge dinv gather and
// halves gather bytes.
__global__ void k_scale(const float* __restrict__ h, const float* __restrict__ dinv,
                        unsigned* __restrict__ hs) {
    int idx = blockIdx.x * 256 + threadIdx.x;   // 3,200,000 uints exactly
    int node = idx >> 6;
    float di = dinv[node];
    float2 hv = ((const float2*)h)[idx];
    hs[idx] = pack2(hv.x * di, hv.y * di);
}

__global__ void k_fill(const int* __restrict__ edge, const int* __restrict__ offs,
                       int* __restrict__ fill, int* __restrict__ csr) {
    int e = blockIdx.x * 256 + threadIdx.x;
    if (e < N_EDGES) {
        int dst = edge[N_EDGES + e];
        int src = edge[e];
        int pos = offs[dst] + atomicAdd(&fill[dst], 1);
        csr[pos] = src;
    }
}

__global__ __launch_bounds__(256) void
k_agg_snn(const unsigned* __restrict__ hs,
          const int* __restrict__ offs, const int* __restrict__ cnt,
          const float* __restrict__ dinv, const int* __restrict__ csr,
          float* __restrict__ out) {
    int node = blockIdx.x * 4 + (threadIdx.x >> 6);   // one wave per node
    int lane = threadIdx.x & 63;                      // lane owns dims 2l, 2l+1

    unsigned p = hs[node * 64 + lane];                // self-loop term
    float a0 = bf_lo(p), a1 = bf_hi(p);

    int beg = offs[node];
    int end = beg + cnt[node];
    int j = beg;
    for (; j + 8 <= end; j += 8) {                    // 8 concurrent gathers
        int s0 = csr[j+0], s1 = csr[j+1], s2 = csr[j+2], s3 = csr[j+3];
        int s4 = csr[j+4], s5 = csr[j+5], s6 = csr[j+6], s7 = csr[j+7];
        unsigned q0 = hs[s0*64+lane], q1 = hs[s1*64+lane];
        unsigned q2 = hs[s2*64+lane], q3 = hs[s3*64+lane];
        unsigned q4 = hs[s4*64+lane], q5 = hs[s5*64+lane];
        unsigned q6 = hs[s6*64+lane], q7 = hs[s7*64+lane];
        a0 += bf_lo(q0); a1 += bf_hi(q0);
        a0 += bf_lo(q1); a1 += bf_hi(q1);
        a0 += bf_lo(q2); a1 += bf_hi(q2);
        a0 += bf_lo(q3); a1 += bf_hi(q3);
        a0 += bf_lo(q4); a1 += bf_hi(q4);
        a0 += bf_lo(q5); a1 += bf_hi(q5);
        a0 += bf_lo(q6); a1 += bf_hi(q6);
        a0 += bf_lo(q7); a1 += bf_hi(q7);
    }
    for (; j < end; ++j) {
        int s = csr[j];
        unsigned q = hs[s*64+lane];
        a0 += bf_lo(q); a1 += bf_hi(q);
    }

    float di = dinv[node];
    float u0 = a0 * di * 0.1f, u1 = a1 * di * 0.1f;   // STEP_SIZE
    float z0 = 0.f, z1 = 0.f;
    float2* out2 = (float2*)out;
    size_t baseo = (size_t)node * 64 + lane;
    const size_t plane = (size_t)N_NODES * 64;        // one t-plane in float2
#pragma unroll
    for (int t = 0; t < T_STEPS; ++t) {
        float H0 = z0 + (u0 - z0) * 0.5f;             // TAU = 2
        float H1 = z1 + (u1 - z1) * 0.5f;
        float o0 = (H0 >= 1.0f) ? 1.0f : 0.0f;        // V_THRESHOLD = 1
        float o1 = (H1 >= 1.0f) ? 1.0f : 0.0f;
        z0 = H0 - o0;
        z1 = H1 - o1;
        out2[(size_t)t * plane + baseo] = make_float2(o0, o1);             // o_seq
        out2[(size_t)(T_STEPS + t) * plane + baseo] = make_float2(z0, z1); // z_seq
    }
}

extern "C" void kernel_launch(void* const* d_in, const int* in_sizes, int n_in,
                              void* d_out, int out_size, void* d_ws, size_t ws_size,
                              hipStream_t stream) {
    const float* x  = (const float*)d_in[0];
    const float* W  = (const float*)d_in[1];
    const int*   ei = (const int*)d_in[2];
    float* out = (float*)d_out;

    char* ws = (char*)d_ws;
    float*          h     = (float*)(ws + 0);
    unsigned*       hs    = (unsigned*)(ws + 25600000);
    unsigned short* Wt_hi = (unsigned short*)(ws + 38400000);
    unsigned short* Wt_lo = (unsigned short*)(ws + 38465536);
    int*            cnt   = (int*)(ws + 38531072);
    int*            fill  = (int*)(ws + 38731072);
    int*            offs  = (int*)(ws + 38931072);
    float*          dinv  = (float*)(ws + 39131072);
    int*            csr   = (int*)(ws + 39331072);

    hipMemsetAsync(ws + 38531072, 0, 400000, stream);   // cnt + fill

    k_prep_w<<<128, 256, 0, stream>>>(W, Wt_hi, Wt_lo);
    k_gemm_count<<<782, 256, 0, stream>>>(x, Wt_hi, Wt_lo, h, ei, cnt);
    k_scan<<<1, 1024, 0, stream>>>(cnt, offs, dinv);
    k_scale<<<12500, 256, 0, stream>>>(h, dinv, hs);
    k_fill<<<6250, 256, 0, stream>>>(ei, offs, fill, csr);
    k_agg_snn<<<12500, 256, 0, stream>>>(hs, offs, cnt, dinv, csr, out);
}

// Round 4
// 709.312 us; speedup vs baseline: 1.1904x; 1.1129x over previous
//
#include <hip/hip_runtime.h>
#include <hip/hip_bf16.h>

#define N_NODES 50000
#define N_EDGES 1600000
#define IN_DIM  256
#define OUT_DIM 128
#define T_STEPS 8

typedef __attribute__((ext_vector_type(8))) short bf16x8;
typedef __attribute__((ext_vector_type(4))) float f32x4;

// ---- ws layout (bytes) ----
// hs    : bf16 [N*128]    @ 0           (12,800,000)  hs[i] = bf16(dinv[i]*h[i])
// Wt_hi : bf16 [128*256]  @ 12,800,000  (65,536)
// Wt_lo : bf16 [128*256]  @ 12,865,536  (65,536)
// cnt   : int  [N]        @ 12,931,072  (200,000)   (memset to 0)
// fill  : int  [N]        @ 13,131,072  (200,000)   (init = offs by k_scanC)
// offs  : int  [N]        @ 13,331,072  (200,000)
// dinv  : f32  [N]        @ 13,531,072  (200,000)
// part  : int  [64]       @ 13,731,072  (256)
// csr   : int  [E]        @ 13,731,328  (6,400,000)

__device__ inline unsigned short bf_hi_trunc(float x) {
    return (unsigned short)(__float_as_uint(x) >> 16);
}
__device__ inline float bf_to_f(unsigned short u) {
    return __uint_as_float((unsigned)u << 16);
}
__device__ inline unsigned short f2bf_rne(float a) {
    __hip_bfloat16 t = __float2bfloat16(a);
    return *(unsigned short*)&t;
}
__device__ inline float bf_lo(unsigned p) { return __uint_as_float(p << 16); }
__device__ inline float bf_hi(unsigned p) { return __uint_as_float(p & 0xffff0000u); }

// W split (hi/lo bf16, transposed) + edge-dst histogram (int4 edge loads).
__global__ __launch_bounds__(256) void
k_prep_count(const float* __restrict__ W,
             unsigned short* __restrict__ Wt_hi,
             unsigned short* __restrict__ Wt_lo,
             const int* __restrict__ edge, int* __restrict__ cnt) {
    int idx = blockIdx.x * 256 + threadIdx.x;   // 204800 threads
    const int4* dst4 = (const int4*)(edge + N_EDGES);
    for (int e = idx; e < N_EDGES / 4; e += 800 * 256) {
        int4 d = dst4[e];
        atomicAdd(&cnt[d.x], 1);
        atomicAdd(&cnt[d.y], 1);
        atomicAdd(&cnt[d.z], 1);
        atomicAdd(&cnt[d.w], 1);
    }
    if (idx < 32768) {
        int n = idx >> 8;      // out dim
        int k = idx & 255;     // in dim
        float w = W[k * OUT_DIM + n];
        unsigned short hi = bf_hi_trunc(w);
        Wt_hi[idx] = hi;
        Wt_lo[idx] = f2bf_rne(w - bf_to_f(hi));
    }
}

// ---- 3-phase exclusive scan of cnt[50000] (12500 int4 per phase-block) ----
__global__ __launch_bounds__(256) void
k_scanA(const int* __restrict__ cnt, int* __restrict__ part) {
    int t = threadIdx.x;
    int i4 = blockIdx.x * 256 + t;
    int4 v = make_int4(0, 0, 0, 0);
    if (i4 < 12500) v = ((const int4*)cnt)[i4];
    int s = v.x + v.y + v.z + v.w;
    __shared__ int sd[256];
    sd[t] = s; __syncthreads();
    for (int o = 128; o > 0; o >>= 1) {
        if (t < o) sd[t] += sd[t + o];
        __syncthreads();
    }
    if (t == 0) part[blockIdx.x] = sd[0];
}

__global__ void k_scanB(int* __restrict__ part) {   // 1 wave
    int l = threadIdx.x;
    int v = (l < 49) ? part[l] : 0;
    int orig = v;
    for (int o = 1; o < 64; o <<= 1) {
        int u = __shfl_up(v, o);
        if (l >= o) v += u;
    }
    if (l < 49) part[l] = v - orig;   // exclusive
}

__global__ __launch_bounds__(256) void
k_scanC(const int* __restrict__ cnt, const int* __restrict__ part,
        int* __restrict__ offs, int* __restrict__ fill,
        float* __restrict__ dinv) {
    int t = threadIdx.x;
    int i4 = blockIdx.x * 256 + t;
    int4 v = make_int4(0, 0, 0, 0);
    if (i4 < 12500) v = ((const int4*)cnt)[i4];
    int s = v.x + v.y + v.z + v.w;
    __shared__ int sd[256];
    sd[t] = s; __syncthreads();
    for (int o = 1; o < 256; o <<= 1) {           // inclusive Hillis-Steele
        int u = (t >= o) ? sd[t - o] : 0;
        __syncthreads();
        sd[t] += u;
        __syncthreads();
    }
    if (i4 < 12500) {
        int base = part[blockIdx.x] + sd[t] - s;  // exclusive
        int4 o4;
        o4.x = base;
        o4.y = o4.x + v.x;
        o4.z = o4.y + v.y;
        o4.w = o4.z + v.z;
        ((int4*)offs)[i4] = o4;
        ((int4*)fill)[i4] = o4;                   // k_fill's running cursor
        float4 d4;
        d4.x = rsqrtf((float)(v.x + 1));
        d4.y = rsqrtf((float)(v.y + 1));
        d4.z = rsqrtf((float)(v.z + 1));
        d4.w = rsqrtf((float)(v.w + 1));
        ((float4*)dinv)[i4] = d4;
    }
}

// GEMM x@W with split-bf16, epilogue writes hs = bf16(dinv[row] * acc).
__global__ __launch_bounds__(256) void
k_gemm(const float* __restrict__ x,
       const unsigned short* __restrict__ Wt_hi,
       const unsigned short* __restrict__ Wt_lo,
       const float* __restrict__ dinv,
       unsigned short* __restrict__ hs) {
    int wave = blockIdx.x * 4 + (threadIdx.x >> 6);
    if (wave >= N_NODES / 16) return;           // 3125 M-tiles of 16 rows
    int lane = threadIdx.x & 63;
    int quad = lane >> 4;
    int r16  = lane & 15;
    int m0 = wave * 16;

    f32x4 acc[8];
#pragma unroll
    for (int nt = 0; nt < 8; ++nt) acc[nt] = (f32x4){0.f, 0.f, 0.f, 0.f};

#pragma unroll
    for (int kt = 0; kt < 8; ++kt) {
        int k0 = kt * 32 + quad * 8;
        const float* xp = x + (size_t)(m0 + r16) * IN_DIM + k0;
        float4 v0 = *(const float4*)xp;
        float4 v1 = *(const float4*)(xp + 4);
        float vv[8] = {v0.x, v0.y, v0.z, v0.w, v1.x, v1.y, v1.z, v1.w};
        union { bf16x8 v; unsigned short u[8]; } ahi, alo;
#pragma unroll
        for (int j = 0; j < 8; ++j) {
            unsigned short hi = bf_hi_trunc(vv[j]);
            ahi.u[j] = hi;
            alo.u[j] = f2bf_rne(vv[j] - bf_to_f(hi));
        }
#pragma unroll
        for (int nt = 0; nt < 8; ++nt) {
            size_t woff = (size_t)(nt * 16 + r16) * IN_DIM + k0;
            bf16x8 bhi = *(const bf16x8*)(Wt_hi + woff);
            bf16x8 blo = *(const bf16x8*)(Wt_lo + woff);
            acc[nt] = __builtin_amdgcn_mfma_f32_16x16x32_bf16(ahi.v, bhi, acc[nt], 0, 0, 0);
            acc[nt] = __builtin_amdgcn_mfma_f32_16x16x32_bf16(alo.v, bhi, acc[nt], 0, 0, 0);
            acc[nt] = __builtin_amdgcn_mfma_f32_16x16x32_bf16(ahi.v, blo, acc[nt], 0, 0, 0);
        }
    }
    float dr[4];
#pragma unroll
    for (int r = 0; r < 4; ++r) dr[r] = dinv[m0 + quad * 4 + r];
#pragma unroll
    for (int nt = 0; nt < 8; ++nt) {
#pragma unroll
        for (int r = 0; r < 4; ++r) {
            int row = m0 + quad * 4 + r;
            int col = nt * 16 + r16;
            hs[(size_t)row * OUT_DIM + col] = f2bf_rne(acc[nt][r] * dr[r]);
        }
    }
}

__global__ __launch_bounds__(256) void
k_fill(const int* __restrict__ edge, int* __restrict__ fill,
       int* __restrict__ csr) {
    int e4 = blockIdx.x * 256 + threadIdx.x;    // 400000 int4 groups
    if (e4 < N_EDGES / 4) {
        int4 s = ((const int4*)edge)[e4];
        int4 d = ((const int4*)(edge + N_EDGES))[e4];
        int p;
        p = atomicAdd(&fill[d.x], 1); csr[p] = s.x;
        p = atomicAdd(&fill[d.y], 1); csr[p] = s.y;
        p = atomicAdd(&fill[d.z], 1); csr[p] = s.z;
        p = atomicAdd(&fill[d.w], 1); csr[p] = s.w;
    }
}

__global__ __launch_bounds__(256) void
k_agg_snn(const unsigned* __restrict__ hs,
          const int* __restrict__ offs, const int* __restrict__ cnt,
          const float* __restrict__ dinv, const int* __restrict__ csr,
          float* __restrict__ out) {
    int node = blockIdx.x * 4 + (threadIdx.x >> 6);   // one wave per node
    int lane = threadIdx.x & 63;                      // lane owns dims 2l, 2l+1

    unsigned p = hs[node * 64 + lane];                // self-loop term
    float a0 = bf_lo(p), a1 = bf_hi(p);

    int beg = __builtin_amdgcn_readfirstlane(offs[node]);
    int end = __builtin_amdgcn_readfirstlane(offs[node] + cnt[node]);
    int j = beg;
    for (; j + 8 <= end; j += 8) {                    // 8 concurrent gathers
        int s0 = csr[j+0], s1 = csr[j+1], s2 = csr[j+2], s3 = csr[j+3];
        int s4 = csr[j+4], s5 = csr[j+5], s6 = csr[j+6], s7 = csr[j+7];
        unsigned q0 = hs[s0*64+lane], q1 = hs[s1*64+lane];
        unsigned q2 = hs[s2*64+lane], q3 = hs[s3*64+lane];
        unsigned q4 = hs[s4*64+lane], q5 = hs[s5*64+lane];
        unsigned q6 = hs[s6*64+lane], q7 = hs[s7*64+lane];
        a0 += bf_lo(q0); a1 += bf_hi(q0);
        a0 += bf_lo(q1); a1 += bf_hi(q1);
        a0 += bf_lo(q2); a1 += bf_hi(q2);
        a0 += bf_lo(q3); a1 += bf_hi(q3);
        a0 += bf_lo(q4); a1 += bf_hi(q4);
        a0 += bf_lo(q5); a1 += bf_hi(q5);
        a0 += bf_lo(q6); a1 += bf_hi(q6);
        a0 += bf_lo(q7); a1 += bf_hi(q7);
    }
    for (; j < end; ++j) {
        int s = csr[j];
        unsigned q = hs[s*64+lane];
        a0 += bf_lo(q); a1 += bf_hi(q);
    }

    float di = dinv[node];
    float u0 = a0 * di * 0.1f, u1 = a1 * di * 0.1f;   // STEP_SIZE
    float z0 = 0.f, z1 = 0.f;
    float2* out2 = (float2*)out;
    size_t baseo = (size_t)node * 64 + lane;
    const size_t plane = (size_t)N_NODES * 64;        // one t-plane in float2
    union F2U { float2 f; unsigned long long u; };
#pragma unroll
    for (int t = 0; t < T_STEPS; ++t) {
        float H0 = z0 + (u0 - z0) * 0.5f;             // TAU = 2
        float H1 = z1 + (u1 - z1) * 0.5f;
        float o0 = (H0 >= 1.0f) ? 1.0f : 0.0f;        // V_THRESHOLD = 1
        float o1 = (H1 >= 1.0f) ? 1.0f : 0.0f;
        z0 = H0 - o0;
        z1 = H1 - o1;
        F2U a, b;
        a.f = make_float2(o0, o1);
        b.f = make_float2(z0, z1);
        // streaming stores: don't evict the hs gather table from L2/L3
        __builtin_nontemporal_store(a.u,
            (unsigned long long*)(out2 + (size_t)t * plane + baseo));
        __builtin_nontemporal_store(b.u,
            (unsigned long long*)(out2 + (size_t)(T_STEPS + t) * plane + baseo));
    }
}

extern "C" void kernel_launch(void* const* d_in, const int* in_sizes, int n_in,
                              void* d_out, int out_size, void* d_ws, size_t ws_size,
                              hipStream_t stream) {
    const float* x  = (const float*)d_in[0];
    const float* W  = (const float*)d_in[1];
    const int*   ei = (const int*)d_in[2];
    float* out = (float*)d_out;

    char* ws = (char*)d_ws;
    unsigned short* hs    = (unsigned short*)(ws + 0);
    unsigned short* Wt_hi = (unsigned short*)(ws + 12800000);
    unsigned short* Wt_lo = (unsigned short*)(ws + 12865536);
    int*            cnt   = (int*)(ws + 12931072);
    int*            fill  = (int*)(ws + 13131072);
    int*            offs  = (int*)(ws + 13331072);
    float*          dinv  = (float*)(ws + 13531072);
    int*            part  = (int*)(ws + 13731072);
    int*            csr   = (int*)(ws + 13731328);

    hipMemsetAsync(cnt, 0, 200000, stream);

    k_prep_count<<<800, 256, 0, stream>>>(W, Wt_hi, Wt_lo, ei, cnt);
    k_scanA<<<49, 256, 0, stream>>>(cnt, part);
    k_scanB<<<1, 64, 0, stream>>>(part);
    k_scanC<<<49, 256, 0, stream>>>(cnt, part, offs, fill, dinv);
    k_gemm<<<782, 256, 0, stream>>>(x, Wt_hi, Wt_lo, dinv, hs);
    k_fill<<<1563, 256, 0, stream>>>(ei, fill, csr);
    k_agg_snn<<<12500, 256, 0, stream>>>((const unsigned*)hs, offs, cnt, dinv, csr, out);
}